// Round 18
// baseline (90.672 us; speedup 1.0000x reference)
//
#include <hip/hip_runtime.h>
#include <hip/hip_bf16.h>

#define NN 50000
#define NE 800000
#define NC 128
#define NEG 0.2f
#define BN_EPS 1e-5f
#define NB 391           // ceil(NN/128) dst-buckets, 128 nodes each
#define EPB 2048         // edges per binning block
#define DEPTH 16         // LDS staging depth per bucket (flush = 64B line)
#define CAP 2560         // fixed bucket capacity (mean 2048, sigma 45 -> 11 sigma)
#define CAPR 2688        // rec capacity per bucket = CAP + 128 self-edges
#define GB 391           // gemm blocks = ceil(NN/128)
#define AGGB 2048        // aggregate blocks (grid-stride, 4 nodes per step)

typedef unsigned int u32;
typedef unsigned short u16;
typedef short bf16x8 __attribute__((ext_vector_type(8)));
typedef float f32x4 __attribute__((ext_vector_type(4)));

// workspace layout (4-byte units)
#define OFF_H       0          // NN*NC bf16 (3.2M words)
#define OFF_ACCUM   3200000    // NN*NC bf16 (3.2M words), node-major
#define OFF_ASRC    6400000    // NN
#define OFF_ADST    6450000    // NN
#define OFF_GCUR    6500000    // 512  <- zeroed in k_prep
#define OFF_GSUM    6500512    // 128 (plain-stored)
#define OFF_GSUMSQ  6500640    // 128
#define OFF_BEG     6500768    // NN
#define OFF_ENDA    6550768    // NN
#define OFF_WINV    6600768    // NN
#define OFF_BIN     6650768    // NB*CAP = 1000960
#define OFF_REC     7651728    // NB*CAPR = 1051008 (packed: src u16 | bf16 w)
#define OFF_WB      8702736    // 8192 u32 (W in bf16 MFMA-frag order)
#define OFF_PS      8710928    // AGGB*128 partial sums
#define OFF_PQ      8973072    // AGGB*128 partial sumsqs
#define OFF_WSEND   9235216    // ~36.9 MB
#define NZERO       512        // words zeroed each launch (gcur)

__device__ __forceinline__ float leaky(float e) { return (e >= 0.f) ? e : NEG * e; }

__device__ __forceinline__ u16 f2b(float f) {   // fp32 -> bf16 RNE
  union { float f; u32 u; } v; v.f = f;
  u32 u = v.u;
  return (u16)((u + 0x7fffu + ((u >> 16) & 1u)) >> 16);
}
__device__ __forceinline__ float blo(u32 u) {
  union { u32 u; float f; } v; v.u = u << 16; return v.f;
}
__device__ __forceinline__ float bhi(u32 u) {
  union { u32 u; float f; } v; v.u = u & 0xffff0000u; return v.f;
}

__device__ __forceinline__ bool ei_is64(const void* ei_raw) {
  const unsigned long long* p64 = (const unsigned long long*)ei_raw;
  bool is64 = true;
#pragma unroll
  for (int k = 0; k < 8; ++k) is64 = is64 && (p64[k] < (unsigned long long)NN);
  return is64;
}

// ---- pack W into MFMA B-fragment order (bf16) + zero gcur -----------------
__global__ __launch_bounds__(256) void k_prep(
    const float* __restrict__ W, u32* __restrict__ Wb32, int* __restrict__ zbase) {
  if (blockIdx.x == 0) {
    for (int i = threadIdx.x; i < NZERO; i += 256) zbase[i] = 0;
  }
  int q = blockIdx.x * 256 + threadIdx.x;   // 2048 slots
  if (q >= 2048) return;
  int f = q >> 6, l = q & 63;
  int n = f >> 2, s = f & 3;
  int col = 16 * n + (l & 15);
  int kb = 32 * s + 8 * (l >> 4);
#pragma unroll
  for (int j2 = 0; j2 < 4; ++j2) {
    u16 e0 = f2b(W[(kb + 2 * j2) * NC + col]);
    u16 e1 = f2b(W[(kb + 2 * j2 + 1) * NC + col]);
    Wb32[q * 4 + j2] = ((u32)e1 << 16) | e0;
  }
}

// ---- fused: h = x@W via MFMA (blocks 0..GB-1) || edge binning -------------
__global__ __launch_bounds__(256) void k_gemm_bin(
    const float* __restrict__ x, const u16* __restrict__ Wb,
    const float* __restrict__ attS, const float* __restrict__ attD,
    u16* __restrict__ h, float* __restrict__ a_src, float* __restrict__ a_dst,
    const void* __restrict__ ei_raw, int* __restrict__ gcur, u32* __restrict__ bin) {
  __shared__ int cnt[NB];
  __shared__ u32 buf[NB * DEPTH];   // 25 KB
  const int t = threadIdx.x;

  if (blockIdx.x >= GB) {                 // ---- bin role ----
    for (int i = t; i < NB; i += 256) cnt[i] = 0;
    __syncthreads();
    bool is64 = ei_is64(ei_raw);
    int base = (blockIdx.x - GB) * EPB;
#pragma unroll
    for (int k = 0; k < 8; ++k) {
      int idx = base + k * 256 + t;
      if (idx >= NE) continue;
      int s, d;
      if (is64) {
        s = (int)((const long long*)ei_raw)[idx];
        d = (int)((const long long*)ei_raw)[NE + idx];
      } else {
        s = ((const int*)ei_raw)[idx];
        d = ((const int*)ei_raw)[NE + idx];
      }
      int b = d >> 7;
      u32 pack = (u32)s | ((u32)(d & 127) << 16);
      int p = atomicAdd(&cnt[b], 1);
      if (p < DEPTH) buf[b * DEPTH + p] = pack;
      else {               // rare overflow: direct scattered write
        int g = atomicAdd(&gcur[b], 1);
        if (g < CAP) bin[b * CAP + g] = pack;
      }
    }
    __syncthreads();
    for (int b = t; b < NB; b += 256) {
      int c = min(cnt[b], DEPTH);
      if (c > 0) {
        int g = atomicAdd(&gcur[b], c);
        int lim = min(c, max(0, CAP - g));
        int gp = b * CAP + g;
#pragma unroll 4
        for (int i = 0; i < lim; ++i) bin[gp + i] = buf[b * DEPTH + i];
      }
    }
    return;
  }

  // ---- GEMM role ----
  const int l = t & 63;
  const int r0 = blockIdx.x * 128 + (t >> 6) * 32;
  const int lr = l & 15;                  // row-in-tile / col-in-frag
  const int kg = l >> 4;                  // k-group

  f32x4 acc[2][8];
#pragma unroll
  for (int t2 = 0; t2 < 2; ++t2)
#pragma unroll
    for (int n = 0; n < 8; ++n) acc[t2][n] = (f32x4){0.f, 0.f, 0.f, 0.f};

#pragma unroll
  for (int s = 0; s < 4; ++s) {
    bf16x8 bfr[8];
#pragma unroll
    for (int n = 0; n < 8; ++n)
      bfr[n] = *(const bf16x8*)(Wb + ((size_t)((n * 4 + s) * 64 + l)) * 8);

#pragma unroll
    for (int t2 = 0; t2 < 2; ++t2) {
      int arow = r0 + t2 * 16 + lr;
      f32x4 a0 = (f32x4){0.f,0.f,0.f,0.f}, a1 = a0;
      if (arow < NN) {
        const float* xa = x + (size_t)arow * NC + kg * 8 + s * 32;
        a0 = *(const f32x4*)xa;
        a1 = *(const f32x4*)(xa + 4);
      }
      bf16x8 af;
      af[0]=(short)f2b(a0[0]); af[1]=(short)f2b(a0[1]);
      af[2]=(short)f2b(a0[2]); af[3]=(short)f2b(a0[3]);
      af[4]=(short)f2b(a1[0]); af[5]=(short)f2b(a1[1]);
      af[6]=(short)f2b(a1[2]); af[7]=(short)f2b(a1[3]);
#pragma unroll
      for (int n = 0; n < 8; ++n)
        acc[t2][n] = __builtin_amdgcn_mfma_f32_16x16x32_bf16(af, bfr[n], acc[t2][n], 0, 0, 0);
    }
  }

  float attS_r[8], attD_r[8];
#pragma unroll
  for (int n = 0; n < 8; ++n) {
    attS_r[n] = attS[16 * n + lr];
    attD_r[n] = attD[16 * n + lr];
  }
#pragma unroll
  for (int t2 = 0; t2 < 2; ++t2) {
#pragma unroll
    for (int q = 0; q < 4; ++q) {
      int row = r0 + t2 * 16 + kg * 4 + q;
      bool rok = row < NN;
      float sA = 0.f, sD = 0.f;
#pragma unroll
      for (int n = 0; n < 8; ++n) {
        float v = acc[t2][n][q];
        sA += v * attS_r[n];
        sD += v * attD_r[n];
        if (rok) h[(size_t)row * NC + 16 * n + lr] = f2b(v);
      }
      sA += __shfl_xor(sA, 1); sD += __shfl_xor(sD, 1);
      sA += __shfl_xor(sA, 2); sD += __shfl_xor(sD, 2);
      sA += __shfl_xor(sA, 4); sD += __shfl_xor(sD, 4);
      sA += __shfl_xor(sA, 8); sD += __shfl_xor(sD, 8);
      if (lr == 0 && rok) { a_src[row] = sA; a_dst[row] = sD; }
    }
  }
}

// ---- per-bucket CSR build (512 thr): sort-by-dst, packed records ----------
// rec[i] = src u16 | bf16(w) << 16; node's region = [begA, endA) incl self.
// winv computed from the bf16-ROUNDED weights (consistent with numerator).
__global__ __launch_bounds__(512) void k_build(
    const int* __restrict__ gcur, const u32* __restrict__ bin,
    const float* __restrict__ a_src, const float* __restrict__ a_dst,
    int* __restrict__ begA, int* __restrict__ endA, float* __restrict__ winv,
    u32* __restrict__ rec) {
  __shared__ int cnt[128], bs[128], cur[128];
  __shared__ float aDl[128], wsh[128];
  int t = threadIdx.x;
  int b = blockIdx.x;
  int nbase = b << 7;
  int nmax = min(128, NN - nbase);
  int ebeg = b * CAP;
  int rbeg = b * CAPR;
  int E = min(gcur[b], CAP);
  if (t < 128) {
    cnt[t] = 0; wsh[t] = 0.f;
    if (t < nmax) aDl[t] = a_dst[nbase + t];
  }
  __syncthreads();
  for (int i = t; i < E; i += 512)
    atomicAdd(&cnt[bin[ebeg + i] >> 16], 1);
  __syncthreads();
  if (t < 128) bs[t] = cnt[t];
  __syncthreads();
  for (int off = 1; off < 128; off <<= 1) {
    int xv = (t < 128 && t >= off) ? bs[t - off] : 0;
    __syncthreads();
    if (t < 128) bs[t] += xv;
    __syncthreads();
  }
  if (t < 128) {
    bs[t] -= cnt[t];          // exclusive
    cur[t] = 0;
  }
  __syncthreads();
  for (int i = t; i < E; i += 512) {
    u32 e = bin[ebeg + i];
    int s = e & 0xFFFF;
    int ld = e >> 16;
    int p = atomicAdd(&cur[ld], 1);
    int pos = rbeg + bs[ld] + ld + p;    // +ld reserves one self-slot per prior node
    u16 wb = f2b(__expf(leaky(a_src[s] + aDl[ld])));
    rec[pos] = (u32)s | ((u32)wb << 16);
    atomicAdd(&wsh[ld], blo((u32)wb));   // accumulate the ROUNDED weight
  }
  __syncthreads();
  if (t < nmax) {
    int node = nbase + t;
    int bg = rbeg + bs[t] + t;
    int cn = cnt[t];
    u16 wb = f2b(__expf(leaky(a_src[node] + aDl[t])));
    rec[bg + cn] = (u32)node | ((u32)wb << 16);   // self edge appended at end
    begA[node] = bg;
    endA[node] = bg + cn + 1;
    winv[node] = 1.f / (wsh[t] + blo((u32)wb));
  }
}

// ---- per-dst gather: uniform packed rec stream, double-buffered batches ---
__global__ __launch_bounds__(256) void k_aggregate(
    const int* __restrict__ begA, const int* __restrict__ endA,
    const u32* __restrict__ rec, const float* __restrict__ winv,
    const u16* __restrict__ h, u32* __restrict__ accum,
    float* __restrict__ partS, float* __restrict__ partQ) {
  int t = threadIdx.x;
  int l = t & 63;                      // lane owns channels 2l, 2l+1
  int wv = t >> 6;
  const u32* h32 = (const u32*)h;      // row d at h32[d*64 + l]
  float cs0 = 0.f, cs1 = 0.f, cq0 = 0.f, cq1 = 0.f;

#define P1(EJ, A)                                                          \
  {                                                                        \
    int sj = __builtin_amdgcn_readfirstlane((int)((EJ) & 0xFFFFu));        \
    float wj = bhi(EJ);                                                    \
    u32 g = h32[(size_t)sj * 64 + l];                                      \
    A.x += wj * blo(g);                                                    \
    A.y += wj * bhi(g);                                                    \
  }

  for (int d = blockIdx.x * 4 + wv; d < NN; d += AGGB * 4) {
    int beg = __builtin_amdgcn_readfirstlane(begA[d]);
    int end = __builtin_amdgcn_readfirstlane(endA[d]);

    float2 a0 = make_float2(0.f, 0.f), a1 = a0, a2 = a0, a3 = a0;
    int nfull = (end - beg) >> 3;      // full 8-record batches
    int j = beg;
    u32 c0, c1, c2, c3, c4, c5, c6, c7;
    if (nfull > 0) {                   // prime current batch (scalar loads)
      const u32* rp = rec + j;
      c0 = rp[0]; c1 = rp[1]; c2 = rp[2]; c3 = rp[3];
      c4 = rp[4]; c5 = rp[5]; c6 = rp[6]; c7 = rp[7];
    }
    for (int bnum = 1; bnum < nfull; ++bnum) {
      const u32* rp = rec + j + 8;     // issue NEXT batch before processing
      u32 n0 = rp[0], n1 = rp[1], n2 = rp[2], n3 = rp[3];
      u32 n4 = rp[4], n5 = rp[5], n6 = rp[6], n7 = rp[7];
      P1(c0, a0) P1(c1, a1) P1(c2, a2) P1(c3, a3)
      P1(c4, a0) P1(c5, a1) P1(c6, a2) P1(c7, a3)
      c0 = n0; c1 = n1; c2 = n2; c3 = n3;
      c4 = n4; c5 = n5; c6 = n6; c7 = n7;
      j += 8;
    }
    if (nfull > 0) {                   // drain last full batch
      P1(c0, a0) P1(c1, a1) P1(c2, a2) P1(c3, a3)
      P1(c4, a0) P1(c5, a1) P1(c6, a2) P1(c7, a3)
      j += 8;
    }
    for (; j < end; ++j) {             // remainder
      u32 e0 = rec[j];
      P1(e0, a0)
    }

    float inv = winv[d];
    float ox = (a0.x + a1.x + a2.x + a3.x) * inv;
    float oy = (a0.y + a1.y + a2.y + a3.y) * inv;
    accum[(size_t)d * 64 + l] = ((u32)f2b(oy) << 16) | f2b(ox);
    cs0 += ox; cs1 += oy;
    cq0 += ox * ox; cq1 += oy * oy;
  }
#undef P1

  // block-combine the 4 waves' per-lane stats, plain-store partials
  __shared__ float2 shS[256], shQ[256];
  shS[t] = make_float2(cs0, cs1);
  shQ[t] = make_float2(cq0, cq1);
  __syncthreads();
  if (t < 64) {
    float2 a = shS[t], b = shQ[t];
#pragma unroll
    for (int g = 1; g < 4; ++g) {
      float2 s2v = shS[g * 64 + t], q2 = shQ[g * 64 + t];
      a.x += s2v.x; a.y += s2v.y;
      b.x += q2.x;  b.y += q2.y;
    }
    partS[blockIdx.x * 128 + 2 * t]     = a.x;
    partS[blockIdx.x * 128 + 2 * t + 1] = a.y;
    partQ[blockIdx.x * 128 + 2 * t]     = b.x;
    partQ[blockIdx.x * 128 + 2 * t + 1] = b.y;
  }
}

// ---- stats stage 2: parallel reduce partials (256 blocks) -----------------
__global__ __launch_bounds__(256) void k_stats2(
    const float* __restrict__ partS, const float* __restrict__ partQ,
    float* __restrict__ gsum, float* __restrict__ gsumsq) {
  __shared__ float shw[4];
  int t = threadIdx.x;
  int b = blockIdx.x;
  int c = b & 127;
  const float* src = (b >> 7) ? partQ : partS;
  float a = 0.f;
#pragma unroll
  for (int i = t; i < AGGB; i += 256) a += src[(size_t)i * 128 + c];
  for (int off = 32; off > 0; off >>= 1) a += __shfl_xor(a, off);
  if ((t & 63) == 0) shw[t >> 6] = a;
  __syncthreads();
  if (t == 0) {
    float r = shw[0] + shw[1] + shw[2] + shw[3];
    if (b >> 7) gsumsq[c] = r;
    else        gsum[c] = r;
  }
}

// ---- BatchNorm (training stats) + ReLU: bf16 accum -> fp32 out ------------
__global__ __launch_bounds__(256) void k_bn(
    const u32* __restrict__ accum, const float* __restrict__ gsum,
    const float* __restrict__ gsumsq, const float* __restrict__ gamma,
    const float* __restrict__ beta, float* __restrict__ out) {
  int i4 = blockIdx.x * 256 + threadIdx.x;
  if (i4 >= NN * NC / 4) return;
  int c4 = (i4 * 4) & 127;
  f32x4 gs = *(const f32x4*)&gsum[c4];
  f32x4 gq = *(const f32x4*)&gsumsq[c4];
  f32x4 ga = *(const f32x4*)&gamma[c4];
  f32x4 be = *(const f32x4*)&beta[c4];
  u32 p0 = accum[(size_t)i4 * 2];
  u32 p1 = accum[(size_t)i4 * 2 + 1];
  f32x4 v = (f32x4){blo(p0), bhi(p0), blo(p1), bhi(p1)};
  f32x4 o;
#pragma unroll
  for (int j = 0; j < 4; ++j) {
    float mean = gs[j] * (1.0f / NN);
    float var = gq[j] * (1.0f / NN) - mean * mean;
    float inv = rsqrtf(var + BN_EPS);
    float y = (v[j] - mean) * inv * ga[j] + be[j];
    o[j] = (y > 0.f) ? y : 0.f;
  }
  *(f32x4*)&out[(size_t)i4 * 4] = o;
}

extern "C" void kernel_launch(void* const* d_in, const int* in_sizes, int n_in,
                              void* d_out, int out_size, void* d_ws, size_t ws_size,
                              hipStream_t stream) {
  const float* x    = (const float*)d_in[0];
  const void*  ei   = d_in[1];
  // d_in[2] = edge_attr (ignored: edge_dim=None in reference)
  const float* W    = (const float*)d_in[3];
  const float* attS = (const float*)d_in[4];
  const float* attD = (const float*)d_in[5];
  // d_in[6] = bias: cancels under BN mean-subtraction (and is zeros)
  const float* gamma = (const float*)d_in[7];
  const float* beta  = (const float*)d_in[8];

  float* ws     = (float*)d_ws;
  u16*   h      = (u16*)(ws + OFF_H);
  u32*   accum  = (u32*)(ws + OFF_ACCUM);
  float* a_src  = ws + OFF_ASRC;
  float* a_dst  = ws + OFF_ADST;
  int*   gcur   = (int*)(ws + OFF_GCUR);
  float* gsum   = ws + OFF_GSUM;
  float* gsumsq = ws + OFF_GSUMSQ;
  int*   begA   = (int*)(ws + OFF_BEG);
  int*   endA   = (int*)(ws + OFF_ENDA);
  float* winv   = ws + OFF_WINV;
  u32*   bin    = (u32*)(ws + OFF_BIN);
  u32*   rec    = (u32*)(ws + OFF_REC);
  u32*   wb32   = (u32*)(ws + OFF_WB);
  float* partS  = ws + OFF_PS;
  float* partQ  = ws + OFF_PQ;

  const int nbin = (NE + EPB - 1) / EPB;  // 391
  k_prep<<<8, 256, 0, stream>>>(W, wb32, gcur);
  k_gemm_bin<<<GB + nbin, 256, 0, stream>>>(x, (const u16*)wb32, attS, attD,
                                            h, a_src, a_dst, ei, gcur, bin);
  k_build<<<NB, 512, 0, stream>>>(gcur, bin, a_src, a_dst, begA, endA, winv, rec);
  k_aggregate<<<AGGB, 256, 0, stream>>>(begA, endA, rec, winv, h,
                                        accum, partS, partQ);
  k_stats2<<<256, 256, 0, stream>>>(partS, partQ, gsum, gsumsq);
  k_bn<<<(NN * NC / 4 + 255) / 256, 256, 0, stream>>>(accum, gsum, gsumsq, gamma, beta,
                                                      (float*)d_out);
}

// Round 19
// 89.247 us; speedup vs baseline: 1.0160x; 1.0160x over previous
//
#include <hip/hip_runtime.h>
#include <hip/hip_bf16.h>

#define NN 50000
#define NE 800000
#define NC 128
#define NEG 0.2f
#define BN_EPS 1e-5f
#define NB 391           // ceil(NN/128) dst-buckets, 128 nodes each
#define EPB 2048         // edges per binning block
#define DEPTH 16         // LDS staging depth per bucket (flush = 64B line)
#define CAP 2560         // fixed bucket capacity (mean 2048, sigma 45 -> 11 sigma)
#define CAPR 2688        // rec capacity per bucket = CAP + 128 self-edges
#define GB 391           // gemm blocks = ceil(NN/128)
#define AGGB 2048        // aggregate blocks (grid-stride, 4 nodes per step)

typedef unsigned int u32;
typedef unsigned short u16;
typedef short bf16x8 __attribute__((ext_vector_type(8)));
typedef float f32x4 __attribute__((ext_vector_type(4)));

// workspace layout (4-byte units)
#define OFF_H       0          // NN*NC bf16 (3.2M words)
#define OFF_ACCUM   3200000    // NN*NC bf16 (3.2M words), node-major
#define OFF_ASRC    6400000    // NN
#define OFF_ADST    6450000    // NN
#define OFF_GCUR    6500000    // 512  <- zeroed in k_prep
#define OFF_GSUM    6500512    // 128 (plain-stored)
#define OFF_GSUMSQ  6500640    // 128
#define OFF_BEG     6500768    // NN
#define OFF_ENDA    6550768    // NN
#define OFF_WINV    6600768    // NN
#define OFF_BIN     6650768    // NB*CAP = 1000960
#define OFF_REC     7651728    // NB*CAPR = 1051008 (packed: src u16 | bf16 w)
#define OFF_WB      8702736    // 8192 u32 (W in bf16 MFMA-frag order)
#define OFF_PS      8710928    // AGGB*128 partial sums
#define OFF_PQ      8973072    // AGGB*128 partial sumsqs
#define OFF_WSEND   9235216    // ~36.9 MB
#define NZERO       512        // words zeroed each launch (gcur)

__device__ __forceinline__ float leaky(float e) { return (e >= 0.f) ? e : NEG * e; }

__device__ __forceinline__ u16 f2b(float f) {   // fp32 -> bf16 RNE
  union { float f; u32 u; } v; v.f = f;
  u32 u = v.u;
  return (u16)((u + 0x7fffu + ((u >> 16) & 1u)) >> 16);
}
__device__ __forceinline__ float blo(u32 u) {
  union { u32 u; float f; } v; v.u = u << 16; return v.f;
}
__device__ __forceinline__ float bhi(u32 u) {
  union { u32 u; float f; } v; v.u = u & 0xffff0000u; return v.f;
}

__device__ __forceinline__ bool ei_is64(const void* ei_raw) {
  const unsigned long long* p64 = (const unsigned long long*)ei_raw;
  bool is64 = true;
#pragma unroll
  for (int k = 0; k < 8; ++k) is64 = is64 && (p64[k] < (unsigned long long)NN);
  return is64;
}

// ---- pack W into MFMA B-fragment order (bf16) + zero gcur -----------------
__global__ __launch_bounds__(256) void k_prep(
    const float* __restrict__ W, u32* __restrict__ Wb32, int* __restrict__ zbase) {
  if (blockIdx.x == 0) {
    for (int i = threadIdx.x; i < NZERO; i += 256) zbase[i] = 0;
  }
  int q = blockIdx.x * 256 + threadIdx.x;   // 2048 slots
  if (q >= 2048) return;
  int f = q >> 6, l = q & 63;
  int n = f >> 2, s = f & 3;
  int col = 16 * n + (l & 15);
  int kb = 32 * s + 8 * (l >> 4);
#pragma unroll
  for (int j2 = 0; j2 < 4; ++j2) {
    u16 e0 = f2b(W[(kb + 2 * j2) * NC + col]);
    u16 e1 = f2b(W[(kb + 2 * j2 + 1) * NC + col]);
    Wb32[q * 4 + j2] = ((u32)e1 << 16) | e0;
  }
}

// ---- fused: h = x@W via MFMA (blocks 0..GB-1) || edge binning -------------
__global__ __launch_bounds__(256) void k_gemm_bin(
    const float* __restrict__ x, const u16* __restrict__ Wb,
    const float* __restrict__ attS, const float* __restrict__ attD,
    u16* __restrict__ h, float* __restrict__ a_src, float* __restrict__ a_dst,
    const void* __restrict__ ei_raw, int* __restrict__ gcur, u32* __restrict__ bin) {
  __shared__ int cnt[NB];
  __shared__ u32 buf[NB * DEPTH];   // 25 KB
  const int t = threadIdx.x;

  if (blockIdx.x >= GB) {                 // ---- bin role ----
    for (int i = t; i < NB; i += 256) cnt[i] = 0;
    __syncthreads();
    bool is64 = ei_is64(ei_raw);
    int base = (blockIdx.x - GB) * EPB;
#pragma unroll
    for (int k = 0; k < 8; ++k) {
      int idx = base + k * 256 + t;
      if (idx >= NE) continue;
      int s, d;
      if (is64) {
        s = (int)((const long long*)ei_raw)[idx];
        d = (int)((const long long*)ei_raw)[NE + idx];
      } else {
        s = ((const int*)ei_raw)[idx];
        d = ((const int*)ei_raw)[NE + idx];
      }
      int b = d >> 7;
      u32 pack = (u32)s | ((u32)(d & 127) << 16);
      int p = atomicAdd(&cnt[b], 1);
      if (p < DEPTH) buf[b * DEPTH + p] = pack;
      else {               // rare overflow: direct scattered write
        int g = atomicAdd(&gcur[b], 1);
        if (g < CAP) bin[b * CAP + g] = pack;
      }
    }
    __syncthreads();
    for (int b = t; b < NB; b += 256) {
      int c = min(cnt[b], DEPTH);
      if (c > 0) {
        int g = atomicAdd(&gcur[b], c);
        int lim = min(c, max(0, CAP - g));
        int gp = b * CAP + g;
#pragma unroll 4
        for (int i = 0; i < lim; ++i) bin[gp + i] = buf[b * DEPTH + i];
      }
    }
    return;
  }

  // ---- GEMM role ----
  const int l = t & 63;
  const int r0 = blockIdx.x * 128 + (t >> 6) * 32;
  const int lr = l & 15;                  // row-in-tile / col-in-frag
  const int kg = l >> 4;                  // k-group

  f32x4 acc[2][8];
#pragma unroll
  for (int t2 = 0; t2 < 2; ++t2)
#pragma unroll
    for (int n = 0; n < 8; ++n) acc[t2][n] = (f32x4){0.f, 0.f, 0.f, 0.f};

#pragma unroll
  for (int s = 0; s < 4; ++s) {
    bf16x8 bfr[8];
#pragma unroll
    for (int n = 0; n < 8; ++n)
      bfr[n] = *(const bf16x8*)(Wb + ((size_t)((n * 4 + s) * 64 + l)) * 8);

#pragma unroll
    for (int t2 = 0; t2 < 2; ++t2) {
      int arow = r0 + t2 * 16 + lr;
      f32x4 a0 = (f32x4){0.f,0.f,0.f,0.f}, a1 = a0;
      if (arow < NN) {
        const float* xa = x + (size_t)arow * NC + kg * 8 + s * 32;
        a0 = *(const f32x4*)xa;
        a1 = *(const f32x4*)(xa + 4);
      }
      bf16x8 af;
      af[0]=(short)f2b(a0[0]); af[1]=(short)f2b(a0[1]);
      af[2]=(short)f2b(a0[2]); af[3]=(short)f2b(a0[3]);
      af[4]=(short)f2b(a1[0]); af[5]=(short)f2b(a1[1]);
      af[6]=(short)f2b(a1[2]); af[7]=(short)f2b(a1[3]);
#pragma unroll
      for (int n = 0; n < 8; ++n)
        acc[t2][n] = __builtin_amdgcn_mfma_f32_16x16x32_bf16(af, bfr[n], acc[t2][n], 0, 0, 0);
    }
  }

  float attS_r[8], attD_r[8];
#pragma unroll
  for (int n = 0; n < 8; ++n) {
    attS_r[n] = attS[16 * n + lr];
    attD_r[n] = attD[16 * n + lr];
  }
#pragma unroll
  for (int t2 = 0; t2 < 2; ++t2) {
#pragma unroll
    for (int q = 0; q < 4; ++q) {
      int row = r0 + t2 * 16 + kg * 4 + q;
      bool rok = row < NN;
      float sA = 0.f, sD = 0.f;
#pragma unroll
      for (int n = 0; n < 8; ++n) {
        float v = acc[t2][n][q];
        sA += v * attS_r[n];
        sD += v * attD_r[n];
        if (rok) h[(size_t)row * NC + 16 * n + lr] = f2b(v);
      }
      sA += __shfl_xor(sA, 1); sD += __shfl_xor(sD, 1);
      sA += __shfl_xor(sA, 2); sD += __shfl_xor(sD, 2);
      sA += __shfl_xor(sA, 4); sD += __shfl_xor(sD, 4);
      sA += __shfl_xor(sA, 8); sD += __shfl_xor(sD, 8);
      if (lr == 0 && rok) { a_src[row] = sA; a_dst[row] = sD; }
    }
  }
}

// ---- per-bucket CSR build: sort-by-dst, packed (src|bf16 w) records -------
// rec[i] = src u16 | bf16(w) << 16; node's region = [begA, endA) incl self.
// winv computed from the bf16-ROUNDED weights (consistent with numerator).
__global__ __launch_bounds__(256) void k_build(
    const int* __restrict__ gcur, const u32* __restrict__ bin,
    const float* __restrict__ a_src, const float* __restrict__ a_dst,
    int* __restrict__ begA, int* __restrict__ endA, float* __restrict__ winv,
    u32* __restrict__ rec) {
  __shared__ int cnt[128], bs[128], cur[128];
  __shared__ float aDl[128], wsh[128];
  int t = threadIdx.x;
  int b = blockIdx.x;
  int nbase = b << 7;
  int nmax = min(128, NN - nbase);
  int ebeg = b * CAP;
  int rbeg = b * CAPR;
  int E = min(gcur[b], CAP);
  if (t < 128) {
    cnt[t] = 0; wsh[t] = 0.f;
    if (t < nmax) aDl[t] = a_dst[nbase + t];
  }
  __syncthreads();
  for (int i = t; i < E; i += 256)
    atomicAdd(&cnt[bin[ebeg + i] >> 16], 1);
  __syncthreads();
  if (t < 128) bs[t] = cnt[t];
  __syncthreads();
  for (int off = 1; off < 128; off <<= 1) {
    int xv = (t < 128 && t >= off) ? bs[t - off] : 0;
    __syncthreads();
    if (t < 128) bs[t] += xv;
    __syncthreads();
  }
  if (t < 128) {
    bs[t] -= cnt[t];          // exclusive
    cur[t] = 0;
  }
  __syncthreads();
  for (int i = t; i < E; i += 256) {
    u32 e = bin[ebeg + i];
    int s = e & 0xFFFF;
    int ld = e >> 16;
    int p = atomicAdd(&cur[ld], 1);
    int pos = rbeg + bs[ld] + ld + p;    // +ld reserves one self-slot per prior node
    u16 wb = f2b(__expf(leaky(a_src[s] + aDl[ld])));
    rec[pos] = (u32)s | ((u32)wb << 16);
    atomicAdd(&wsh[ld], blo((u32)wb));   // accumulate the ROUNDED weight
  }
  __syncthreads();
  if (t < nmax) {
    int node = nbase + t;
    int bg = rbeg + bs[t] + t;
    int cn = cnt[t];
    u16 wb = f2b(__expf(leaky(a_src[node] + aDl[t])));
    rec[bg + cn] = (u32)node | ((u32)wb << 16);   // self edge appended at end
    begA[node] = bg;
    endA[node] = bg + cn + 1;
    winv[node] = 1.f / (wsh[t] + blo((u32)wb));
  }
}

// ---- per-dst gather: uniform packed rec stream + scalar-address gathers ---
__global__ __launch_bounds__(256) void k_aggregate(
    const int* __restrict__ begA, const int* __restrict__ endA,
    const u32* __restrict__ rec, const float* __restrict__ winv,
    const u16* __restrict__ h, u32* __restrict__ accum,
    float* __restrict__ partS, float* __restrict__ partQ) {
  int t = threadIdx.x;
  int l = t & 63;                      // lane owns channels 2l, 2l+1
  int wv = t >> 6;
  const u32* h32 = (const u32*)h;      // row d at h32[d*64 + l]
  float cs0 = 0.f, cs1 = 0.f, cq0 = 0.f, cq1 = 0.f;

#define P1(EJ, A)                                                          \
  {                                                                        \
    int sj = __builtin_amdgcn_readfirstlane((int)((EJ) & 0xFFFFu));        \
    float wj = bhi(EJ);                                                    \
    u32 g = h32[(size_t)sj * 64 + l];                                      \
    A.x += wj * blo(g);                                                    \
    A.y += wj * bhi(g);                                                    \
  }

  for (int d = blockIdx.x * 4 + wv; d < NN; d += AGGB * 4) {
    int beg = __builtin_amdgcn_readfirstlane(begA[d]);
    int end = __builtin_amdgcn_readfirstlane(endA[d]);

    float2 a0 = make_float2(0.f, 0.f), a1 = a0, a2 = a0, a3 = a0;
    int j = beg;
    for (; j + 8 <= end; j += 8) {
      const u32* rp = rec + j;          // uniform across lanes; L1 broadcasts
      u32 e0 = rp[0], e1 = rp[1], e2 = rp[2], e3 = rp[3];
      u32 e4 = rp[4], e5 = rp[5], e6 = rp[6], e7 = rp[7];
      P1(e0, a0) P1(e1, a1) P1(e2, a2) P1(e3, a3)
      P1(e4, a0) P1(e5, a1) P1(e6, a2) P1(e7, a3)
    }
    for (; j + 2 <= end; j += 2) {
      u32 e0 = rec[j], e1 = rec[j + 1];
      P1(e0, a0) P1(e1, a1)
    }
    if (j < end) {
      u32 e0 = rec[j];
      P1(e0, a0)
    }

    float inv = winv[d];
    float ox = (a0.x + a1.x + a2.x + a3.x) * inv;
    float oy = (a0.y + a1.y + a2.y + a3.y) * inv;
    accum[(size_t)d * 64 + l] = ((u32)f2b(oy) << 16) | f2b(ox);
    cs0 += ox; cs1 += oy;
    cq0 += ox * ox; cq1 += oy * oy;
  }
#undef P1

  // block-combine the 4 waves' per-lane stats, plain-store partials
  __shared__ float2 shS[256], shQ[256];
  shS[t] = make_float2(cs0, cs1);
  shQ[t] = make_float2(cq0, cq1);
  __syncthreads();
  if (t < 64) {
    float2 a = shS[t], b = shQ[t];
#pragma unroll
    for (int g = 1; g < 4; ++g) {
      float2 s2v = shS[g * 64 + t], q2 = shQ[g * 64 + t];
      a.x += s2v.x; a.y += s2v.y;
      b.x += q2.x;  b.y += q2.y;
    }
    partS[blockIdx.x * 128 + 2 * t]     = a.x;
    partS[blockIdx.x * 128 + 2 * t + 1] = a.y;
    partQ[blockIdx.x * 128 + 2 * t]     = b.x;
    partQ[blockIdx.x * 128 + 2 * t + 1] = b.y;
  }
}

// ---- stats stage 2: parallel reduce partials (256 blocks) -----------------
__global__ __launch_bounds__(256) void k_stats2(
    const float* __restrict__ partS, const float* __restrict__ partQ,
    float* __restrict__ gsum, float* __restrict__ gsumsq) {
  __shared__ float shw[4];
  int t = threadIdx.x;
  int b = blockIdx.x;
  int c = b & 127;
  const float* src = (b >> 7) ? partQ : partS;
  float a = 0.f;
#pragma unroll
  for (int i = t; i < AGGB; i += 256) a += src[(size_t)i * 128 + c];
  for (int off = 32; off > 0; off >>= 1) a += __shfl_xor(a, off);
  if ((t & 63) == 0) shw[t >> 6] = a;
  __syncthreads();
  if (t == 0) {
    float r = shw[0] + shw[1] + shw[2] + shw[3];
    if (b >> 7) gsumsq[c] = r;
    else        gsum[c] = r;
  }
}

// ---- BatchNorm (training stats) + ReLU: bf16 accum -> fp32 out ------------
__global__ __launch_bounds__(256) void k_bn(
    const u32* __restrict__ accum, const float* __restrict__ gsum,
    const float* __restrict__ gsumsq, const float* __restrict__ gamma,
    const float* __restrict__ beta, float* __restrict__ out) {
  int i4 = blockIdx.x * 256 + threadIdx.x;
  if (i4 >= NN * NC / 4) return;
  int c4 = (i4 * 4) & 127;
  f32x4 gs = *(const f32x4*)&gsum[c4];
  f32x4 gq = *(const f32x4*)&gsumsq[c4];
  f32x4 ga = *(const f32x4*)&gamma[c4];
  f32x4 be = *(const f32x4*)&beta[c4];
  u32 p0 = accum[(size_t)i4 * 2];
  u32 p1 = accum[(size_t)i4 * 2 + 1];
  f32x4 v = (f32x4){blo(p0), bhi(p0), blo(p1), bhi(p1)};
  f32x4 o;
#pragma unroll
  for (int j = 0; j < 4; ++j) {
    float mean = gs[j] * (1.0f / NN);
    float var = gq[j] * (1.0f / NN) - mean * mean;
    float inv = rsqrtf(var + BN_EPS);
    float y = (v[j] - mean) * inv * ga[j] + be[j];
    o[j] = (y > 0.f) ? y : 0.f;
  }
  *(f32x4*)&out[(size_t)i4 * 4] = o;
}

extern "C" void kernel_launch(void* const* d_in, const int* in_sizes, int n_in,
                              void* d_out, int out_size, void* d_ws, size_t ws_size,
                              hipStream_t stream) {
  const float* x    = (const float*)d_in[0];
  const void*  ei   = d_in[1];
  // d_in[2] = edge_attr (ignored: edge_dim=None in reference)
  const float* W    = (const float*)d_in[3];
  const float* attS = (const float*)d_in[4];
  const float* attD = (const float*)d_in[5];
  // d_in[6] = bias: cancels under BN mean-subtraction (and is zeros)
  const float* gamma = (const float*)d_in[7];
  const float* beta  = (const float*)d_in[8];

  float* ws     = (float*)d_ws;
  u16*   h      = (u16*)(ws + OFF_H);
  u32*   accum  = (u32*)(ws + OFF_ACCUM);
  float* a_src  = ws + OFF_ASRC;
  float* a_dst  = ws + OFF_ADST;
  int*   gcur   = (int*)(ws + OFF_GCUR);
  float* gsum   = ws + OFF_GSUM;
  float* gsumsq = ws + OFF_GSUMSQ;
  int*   begA   = (int*)(ws + OFF_BEG);
  int*   endA   = (int*)(ws + OFF_ENDA);
  float* winv   = ws + OFF_WINV;
  u32*   bin    = (u32*)(ws + OFF_BIN);
  u32*   rec    = (u32*)(ws + OFF_REC);
  u32*   wb32   = (u32*)(ws + OFF_WB);
  float* partS  = ws + OFF_PS;
  float* partQ  = ws + OFF_PQ;

  const int nbin = (NE + EPB - 1) / EPB;  // 391
  k_prep<<<8, 256, 0, stream>>>(W, wb32, gcur);
  k_gemm_bin<<<GB + nbin, 256, 0, stream>>>(x, (const u16*)wb32, attS, attD,
                                            h, a_src, a_dst, ei, gcur, bin);
  k_build<<<NB, 256, 0, stream>>>(gcur, bin, a_src, a_dst, begA, endA, winv, rec);
  k_aggregate<<<AGGB, 256, 0, stream>>>(begA, endA, rec, winv, h,
                                        accum, partS, partQ);
  k_stats2<<<256, 256, 0, stream>>>(partS, partQ, gsum, gsumsq);
  k_bn<<<(NN * NC / 4 + 255) / 256, 256, 0, stream>>>(accum, gsum, gsumsq, gamma, beta,
                                                      (float*)d_out);
}